// Round 1
// baseline (1008.583 us; speedup 1.0000x reference)
//
#include <hip/hip_runtime.h>
#include <hip/hip_bf16.h>
#include <cstdint>
#include <cstddef>

// CoAttention on MI355X.
//   k   = x  @ Wk^T ; q_s = x @ Wqs^T ; q_o = queries @ Wqo^T ; v = values @ Wv^T
//   S_s = q_s k^T /32 + pen ; S_o = q_o k^T /32 + pen
//   p_s = softmax(S_s); p_o = softmax(S_o); out = (p_s + p_o) @ v
// Outputs (fp32, concatenated): out [8,2048,1024], p_self [8,2048,2048]
//
// Workspace layout (needs 201,326,592 B):
//   R0 [0, 134217728):   phase1: xb(32MB) qb(32MB) vb(32MB) W4(8MB) bf16
//                        phase2: scores_other fp32 [8,2048,2048];
//                                p_sum bf16 written in-place (row stride 8192 B)
//   R1 [134217728, +64MB): K_bf16 [8,2048,1024], Vt_bf16 [8,1024,2048]
// d_out reuse: out-region holds Qs/Qo bf16 until final GEMM; p_self region
// holds V-temp until transpose, then raw scores_self, then p_self in place.

#define B_ 8
#define L_ 2048
#define D_ 1024

typedef __attribute__((ext_vector_type(8))) short short8;
typedef __attribute__((ext_vector_type(4))) float floatx4;

__device__ __forceinline__ ushort f2bf(float f) {
  union { float f; uint32_t u; } v; v.f = f;
  return (ushort)((v.u + 0x7FFFu + ((v.u >> 16) & 1u)) >> 16);
}

__device__ __forceinline__ void gload_lds16(const ushort* g, ushort* l) {
  __builtin_amdgcn_global_load_lds(
      (const __attribute__((address_space(1))) void*)g,
      (__attribute__((address_space(3))) void*)l, 16, 0, 0);
}

// C[M,N] = A[M,K] * B[N,K]^T, bf16 inputs, fp32 accum (m97 structure:
// 128x128 tile, BK=32, 4 waves of 64x64, global_load_lds width=16).
// EPI 0: store bf16. EPI 1: store fp32 * scale + (1-mask[col])*-1e5.
// EPI 2: store fp32.
template<int EPI>
__global__ __launch_bounds__(256) void gemm_bt(
    const ushort* __restrict__ A, long long aBatch, int aStride,
    const ushort* __restrict__ Bm, long long bBatch, int bStride,
    void* __restrict__ Cv, long long cBatch, int cStride,
    int K, const float* __restrict__ mask, int maskStride, float scale)
{
  __shared__ alignas(16) ushort lA[128 * 32];
  __shared__ alignas(16) ushort lB[128 * 32];
  const int tid  = threadIdx.x;
  const int lane = tid & 63;
  const int wave = tid >> 6;
  const int z    = blockIdx.z;

  const ushort* Ab = A + (long long)z * aBatch + (long long)blockIdx.x * 128 * aStride;
  const ushort* Bb = Bm + (long long)z * bBatch + (long long)blockIdx.y * 128 * bStride;

  const int wm = (wave & 1) * 64;
  const int wn = (wave >> 1) * 64;

  const floatx4 zero = {0.f, 0.f, 0.f, 0.f};
  floatx4 acc[4][4];
#pragma unroll
  for (int i = 0; i < 4; i++)
#pragma unroll
    for (int j = 0; j < 4; j++) acc[i][j] = zero;

  for (int k0 = 0; k0 < K; k0 += 32) {
    __syncthreads();
#pragma unroll
    for (int j = 0; j < 2; ++j) {
      int lin = j * 256 + tid;
      int row = lin >> 2;          // 4 lanes per 32-elem (64B) row
      int col = (lin & 3) << 3;    // 8 bf16 per 16B chunk
      gload_lds16(Ab + (long long)row * aStride + (k0 + col), lA + lin * 8);
      gload_lds16(Bb + (long long)row * bStride + (k0 + col), lB + lin * 8);
    }
    __syncthreads();

    short8 af[4], bg[4];
#pragma unroll
    for (int i = 0; i < 4; i++) {
      af[i] = *(const short8*)(lA + ((wm + i * 16 + (lane & 15)) * 32 + (lane >> 4) * 8));
      bg[i] = *(const short8*)(lB + ((wn + i * 16 + (lane & 15)) * 32 + (lane >> 4) * 8));
    }
#pragma unroll
    for (int i = 0; i < 4; i++)
#pragma unroll
      for (int j = 0; j < 4; j++)
        acc[i][j] = __builtin_amdgcn_mfma_f32_16x16x32_bf16(af[i], bg[j], acc[i][j], 0, 0, 0);
  }

  // C/D layout (m89-verified): col = lane&15, row = (lane>>4)*4 + r
  const int m0 = blockIdx.x * 128 + wm + (lane >> 4) * 4;
  const int n0 = blockIdx.y * 128 + wn + (lane & 15);

  if (EPI == 0) {
    ushort* C = (ushort*)Cv + (long long)z * cBatch;
#pragma unroll
    for (int i = 0; i < 4; i++)
#pragma unroll
      for (int j = 0; j < 4; j++) {
        int gc = n0 + j * 16;
#pragma unroll
        for (int r = 0; r < 4; r++)
          C[(long long)(m0 + i * 16 + r) * cStride + gc] = f2bf(acc[i][j][r]);
      }
  } else {
    float* C = (float*)Cv + (long long)z * cBatch;
#pragma unroll
    for (int j = 0; j < 4; j++) {
      int gc = n0 + j * 16;
      float pen = 0.f;
      if (EPI == 1) pen = (1.0f - mask[(long long)z * maskStride + gc]) * -100000.0f;
#pragma unroll
      for (int i = 0; i < 4; i++)
#pragma unroll
        for (int r = 0; r < 4; r++) {
          float v = acc[i][j][r];
          if (EPI == 1) v = v * scale + pen;
          C[(long long)(m0 + i * 16 + r) * cStride + gc] = v;
        }
    }
  }
}

// Vt[b][a][k] = V[b][k][a]  (bf16), 64x64 LDS tiles
__global__ __launch_bounds__(256) void transpose_bf16(
    const ushort* __restrict__ V, ushort* __restrict__ Vt)
{
  __shared__ ushort t[64][66];
  const int b = blockIdx.z;
  const int k0 = blockIdx.x * 64;
  const int a0 = blockIdx.y * 64;
  const ushort* Vb = V + (size_t)b * (L_ * D_);
  ushort* Vtb = Vt + (size_t)b * (D_ * L_);
  const int tx = threadIdx.x & 63;
  const int ty = threadIdx.x >> 6;
#pragma unroll
  for (int r = 0; r < 16; ++r) {
    int row = r * 4 + ty;
    t[row][tx] = Vb[(size_t)(k0 + row) * D_ + (a0 + tx)];
  }
  __syncthreads();
#pragma unroll
  for (int r = 0; r < 16; ++r) {
    int row = r * 4 + ty;
    Vtb[(size_t)(a0 + row) * L_ + (k0 + tx)] = t[tx][row];
  }
}

__device__ __forceinline__ float block_red(float v, bool domax, float* red)
{
#pragma unroll
  for (int off = 32; off > 0; off >>= 1) {
    float o = __shfl_xor(v, off, 64);
    v = domax ? fmaxf(v, o) : (v + o);
  }
  __syncthreads();
  if ((threadIdx.x & 63) == 0) red[threadIdx.x >> 6] = v;
  __syncthreads();
  return domax ? fmaxf(fmaxf(red[0], red[1]), fmaxf(red[2], red[3]))
               : (red[0] + red[1] + red[2] + red[3]);
}

// One workgroup per row. Softmax self-row in place (fp32, the p_self output);
// softmax other-row and write p_self+p_other as bf16 in-place over the
// other-row storage (first 4KB of its 8KB row).
__global__ __launch_bounds__(256) void softmax2(float* Sself, float* Sother)
{
  __shared__ float red[4];
  const size_t row = blockIdx.x;
  const int tid = threadIdx.x;
  float* rs = Sself + row * (size_t)L_;
  float* ro = Sother + row * (size_t)L_;

  float vs[8], vo[8];
#pragma unroll
  for (int j = 0; j < 8; j++) vs[j] = rs[tid + j * 256];
#pragma unroll
  for (int j = 0; j < 8; j++) vo[j] = ro[tid + j * 256];

  float ms = -3.0e38f, mo = -3.0e38f;
#pragma unroll
  for (int j = 0; j < 8; j++) { ms = fmaxf(ms, vs[j]); mo = fmaxf(mo, vo[j]); }
  ms = block_red(ms, true, red);
  mo = block_red(mo, true, red);

  float ss = 0.f, so = 0.f;
#pragma unroll
  for (int j = 0; j < 8; j++) {
    vs[j] = __expf(vs[j] - ms); ss += vs[j];
    vo[j] = __expf(vo[j] - mo); so += vo[j];
  }
  ss = block_red(ss, false, red);
  so = block_red(so, false, red);
  const float is = 1.f / ss, io = 1.f / so;

  // all reads of ro completed before the barriers inside block_red above,
  // so the aliasing bf16 write below is safe.
  ushort* rp = (ushort*)ro;
#pragma unroll
  for (int j = 0; j < 8; j++) rs[tid + j * 256] = vs[j] * is;
#pragma unroll
  for (int j = 0; j < 8; j++) rp[tid + j * 256] = f2bf(vs[j] * is + vo[j] * io);
}

// fp32 -> bf16, blockIdx.z selects source; dst slabs contiguous (n4*4 each)
__global__ __launch_bounds__(256) void cvt4(
    const float* __restrict__ s0, const float* __restrict__ s1,
    const float* __restrict__ s2, const float* __restrict__ s3,
    ushort* __restrict__ dst, int n4)
{
  const float* s = (blockIdx.z == 0) ? s0 : (blockIdx.z == 1) ? s1
                   : (blockIdx.z == 2) ? s2 : s3;
  ushort* d = dst + (size_t)blockIdx.z * (size_t)n4 * 4;
  const float4* sv = (const float4*)s;
  ushort4* dv = (ushort4*)d;
  for (int i = blockIdx.x * 256 + threadIdx.x; i < n4; i += gridDim.x * 256) {
    float4 f = sv[i];
    ushort4 o; o.x = f2bf(f.x); o.y = f2bf(f.y); o.z = f2bf(f.z); o.w = f2bf(f.w);
    dv[i] = o;
  }
}

extern "C" void kernel_launch(void* const* d_in, const int* in_sizes, int n_in,
                              void* d_out, int out_size, void* d_ws, size_t ws_size,
                              hipStream_t stream)
{
  const float* x    = (const float*)d_in[0];
  const float* qry  = (const float*)d_in[1];
  const float* val  = (const float*)d_in[2];
  const float* mask = (const float*)d_in[3];
  const float* Wk   = (const float*)d_in[4];
  const float* Wqs  = (const float*)d_in[5];
  const float* Wqo  = (const float*)d_in[6];
  const float* Wv   = (const float*)d_in[7];

  const size_t NE = (size_t)B_ * L_ * D_;  // 16,777,216
  const size_t NW = (size_t)D_ * D_;       // 1,048,576

  float* out   = (float*)d_out;
  float* pself = out + NE;                 // [8,2048,2048] fp32

  char* ws = (char*)d_ws;
  ushort* xb = (ushort*)ws;                // phase-1 R0
  ushort* qb = xb + NE;
  ushort* vb = qb + NE;
  ushort* W4 = vb + NE;                    // 4 x 1M bf16
  float*  sother = (float*)ws;             // phase-2 R0 (overwrites the above)
  ushort* Kb = (ushort*)(ws + (size_t)134217728);  // R1
  ushort* Vt = Kb + NE;

  ushort* Qs   = (ushort*)d_out;           // lives in out-region until final GEMM
  ushort* Qo   = Qs + NE;
  ushort* Vtmp = (ushort*)pself;           // lives in p_self region until transpose

  const float scale = 0.03125f;            // 1/sqrt(1024)

  // 1) fp32 -> bf16 conversions
  cvt4<<<dim3(4096, 1, 3), 256, 0, stream>>>(x, qry, val, nullptr, xb, (int)(NE / 4));
  cvt4<<<dim3(1024, 1, 4), 256, 0, stream>>>(Wk, Wqs, Wqo, Wv, W4, (int)(NW / 4));

  // 2) projections: M=16384, N=1024, K=1024
  dim3 gp(16384 / 128, 1024 / 128, 1);
  gemm_bt<0><<<gp, 256, 0, stream>>>(xb, 0, D_, W4 + 0 * NW, 0, D_, Kb,   0, D_, D_, nullptr, 0, 1.f);
  gemm_bt<0><<<gp, 256, 0, stream>>>(xb, 0, D_, W4 + 1 * NW, 0, D_, Qs,   0, D_, D_, nullptr, 0, 1.f);
  gemm_bt<0><<<gp, 256, 0, stream>>>(qb, 0, D_, W4 + 2 * NW, 0, D_, Qo,   0, D_, D_, nullptr, 0, 1.f);
  gemm_bt<0><<<gp, 256, 0, stream>>>(vb, 0, D_, W4 + 3 * NW, 0, D_, Vtmp, 0, D_, D_, nullptr, 0, 1.f);

  // 3) V -> V^T (per batch)
  transpose_bf16<<<dim3(L_ / 64, D_ / 64, B_), 256, 0, stream>>>(Vtmp, Vt);

  // 4) scores: M=2048, N=2048, K=1024, batched over 8
  dim3 gs(L_ / 128, L_ / 128, B_);
  gemm_bt<1><<<gs, 256, 0, stream>>>(Qs, (long long)L_ * D_, D_, Kb, (long long)L_ * D_, D_,
                                     pself, (long long)L_ * L_, L_, D_, mask, L_, scale);
  gemm_bt<1><<<gs, 256, 0, stream>>>(Qo, (long long)L_ * D_, D_, Kb, (long long)L_ * D_, D_,
                                     sother, (long long)L_ * L_, L_, D_, mask, L_, scale);

  // 5) softmax both score sets; p_self fp32 in place; p_sum bf16 into R0
  softmax2<<<dim3(B_ * L_, 1, 1), 256, 0, stream>>>(pself, sother);

  // 6) out = p_sum @ Vt^T: M=2048, N=1024, K=2048, batched over 8
  dim3 go(L_ / 128, D_ / 128, B_);
  gemm_bt<2><<<go, 256, 0, stream>>>((const ushort*)sother, (long long)L_ * 4096, 4096,
                                     Vt, (long long)D_ * L_, L_,
                                     out, (long long)L_ * D_, D_, L_, nullptr, 0, 1.f);
}

// Round 2
// 888.569 us; speedup vs baseline: 1.1351x; 1.1351x over previous
//
#include <hip/hip_runtime.h>
#include <hip/hip_bf16.h>
#include <cstdint>
#include <cstddef>

// CoAttention on MI355X — round 2.
//   k=x@Wk^T; q_s=x@Wqs^T; q_o=queries@Wqo^T; v=values@Wv^T
//   S_s=q_s k^T/32+pen; S_o=q_o k^T/32+pen; p=softmax; out=(p_s+p_o)@v
// Outputs fp32 concat: out [8,2048,1024], p_self [8,2048,2048].
//
// R2 changes vs R1: BK=64 (two stacked BK=32 LDS tiles, 32 MFMA per barrier
// pair), bf16 score materialization (halves score write + softmax read),
// merged dispatches (proj z=4, scores z=16).
//
// Memory map:
//  ws [0,134MB):  phase1: xb(32M) qb(32M) vb(32M) W4(8M) bf16
//                 phase2: Ss bf16 [8,2048,2048] (67MB) | So bf16 (67MB);
//                         Psum bf16 written in-place over So
//  ws [134,166MB): Vt bf16 [8,1024,2048]
//  d_out ushort view: Qs@0, Qo@NE, Kb@2NE, Vtmp@3NE (all dead before the
//  final writes of out fp32 [0,64MB) and p_self fp32 [64,198MB)).

#define B_ 8
#define L_ 2048
#define D_ 1024

typedef __attribute__((ext_vector_type(8))) short short8;
typedef __attribute__((ext_vector_type(4))) float floatx4;

__device__ __forceinline__ ushort f2bf(float f) {
  union { float f; uint32_t u; } v; v.f = f;
  return (ushort)((v.u + 0x7FFFu + ((v.u >> 16) & 1u)) >> 16);
}
__device__ __forceinline__ float bf2f(ushort u) {
  union { uint32_t u; float f; } v; v.u = ((uint32_t)u) << 16;
  return v.f;
}

__device__ __forceinline__ void gload_lds16(const ushort* g, ushort* l) {
  __builtin_amdgcn_global_load_lds(
      (const __attribute__((address_space(1))) void*)g,
      (__attribute__((address_space(3))) void*)l, 16, 0, 0);
}

// C[M,N] = A[M,K] * B[N,K]^T, bf16 in, fp32 accum. 128x128 tile, BK=64 as
// two m97-layout BK=32 half-tiles (one barrier pair per 64 K-elements).
// MODE 0 (proj):   asel={x,qry,x,val}, bsel=z (W order Wqs,Wqo,Wk,Wv), bf16 C
// MODE 1 (scores): bsel=msel=z&7, bf16 C = acc*scale + pen
// MODE 2 (out):    plain z, fp32 C
template<int MODE>
__global__ __launch_bounds__(256) void gemm_bt(
    const ushort* __restrict__ A, long long aBatch, int aStride,
    const ushort* __restrict__ Bm, long long bBatch, int bStride,
    void* __restrict__ Cv, long long cBatch, int cStride,
    int K, const float* __restrict__ mask, float scale)
{
  __shared__ alignas(16) ushort lA[2][128 * 32];
  __shared__ alignas(16) ushort lB[2][128 * 32];
  const int tid  = threadIdx.x;
  const int lane = tid & 63;
  const int wave = tid >> 6;
  const int z    = blockIdx.z;

  int asel = z, bsel = z, msel = 0;
  if (MODE == 0) { asel = (z & 1) + (z == 3); }      // {0,1,0,2}: x,qry,x,val
  if (MODE == 1) { bsel = z & 7; msel = z & 7; }

  const ushort* Ab = A + (long long)asel * aBatch + (long long)blockIdx.x * 128 * aStride;
  const ushort* Bb = Bm + (long long)bsel * bBatch + (long long)blockIdx.y * 128 * bStride;

  const int wm = (wave & 1) * 64;
  const int wn = (wave >> 1) * 64;

  const floatx4 zero = {0.f, 0.f, 0.f, 0.f};
  floatx4 acc[4][4];
#pragma unroll
  for (int i = 0; i < 4; i++)
#pragma unroll
    for (int j = 0; j < 4; j++) acc[i][j] = zero;

  // staging geometry: 4 lanes per 64B (32-elem) row, 2 passes per half-tile
  const int srow = tid >> 2;
  const int scol = (tid & 3) << 3;

  for (int k0 = 0; k0 < K; k0 += 64) {
    __syncthreads();
#pragma unroll
    for (int h = 0; h < 2; ++h) {
#pragma unroll
      for (int j = 0; j < 2; ++j) {
        int row = srow + j * 64;
        int l   = (j * 256 + tid) * 8;
        gload_lds16(Ab + (long long)row * aStride + (k0 + h * 32 + scol), lA[h] + l);
        gload_lds16(Bb + (long long)row * bStride + (k0 + h * 32 + scol), lB[h] + l);
      }
    }
    __syncthreads();

#pragma unroll
    for (int h = 0; h < 2; ++h) {
      short8 af[4], bg[4];
#pragma unroll
      for (int i = 0; i < 4; i++) {
        af[i] = *(const short8*)(lA[h] + ((wm + i * 16 + (lane & 15)) * 32 + (lane >> 4) * 8));
        bg[i] = *(const short8*)(lB[h] + ((wn + i * 16 + (lane & 15)) * 32 + (lane >> 4) * 8));
      }
#pragma unroll
      for (int i = 0; i < 4; i++)
#pragma unroll
        for (int j = 0; j < 4; j++)
          acc[i][j] = __builtin_amdgcn_mfma_f32_16x16x32_bf16(af[i], bg[j], acc[i][j], 0, 0, 0);
    }
  }

  // C/D layout (m89): col = lane&15, row = (lane>>4)*4 + r
  const int m0 = blockIdx.x * 128 + wm + (lane >> 4) * 4;
  const int n0 = blockIdx.y * 128 + wn + (lane & 15);

  if (MODE == 2) {
    float* C = (float*)Cv + (long long)z * cBatch;
#pragma unroll
    for (int i = 0; i < 4; i++)
#pragma unroll
      for (int j = 0; j < 4; j++)
#pragma unroll
        for (int r = 0; r < 4; r++)
          C[(long long)(m0 + i * 16 + r) * cStride + (n0 + j * 16)] = acc[i][j][r];
  } else {
    ushort* C = (ushort*)Cv + (long long)z * cBatch;
#pragma unroll
    for (int j = 0; j < 4; j++) {
      const int gc = n0 + j * 16;
      float pen = 0.f;
      if (MODE == 1) pen = (1.0f - mask[(long long)msel * L_ + gc]) * -100000.0f;
#pragma unroll
      for (int i = 0; i < 4; i++)
#pragma unroll
        for (int r = 0; r < 4; r++) {
          float v = acc[i][j][r];
          if (MODE == 1) v = v * scale + pen;
          C[(long long)(m0 + i * 16 + r) * cStride + gc] = f2bf(v);
        }
    }
  }
}

// Vt[b][a][k] = V[b][k][a]  (bf16), 64x64 LDS tiles
__global__ __launch_bounds__(256) void transpose_bf16(
    const ushort* __restrict__ V, ushort* __restrict__ Vt)
{
  __shared__ ushort t[64][66];
  const int b = blockIdx.z;
  const int k0 = blockIdx.x * 64;
  const int a0 = blockIdx.y * 64;
  const ushort* Vb = V + (size_t)b * (L_ * D_);
  ushort* Vtb = Vt + (size_t)b * (D_ * L_);
  const int tx = threadIdx.x & 63;
  const int ty = threadIdx.x >> 6;
#pragma unroll
  for (int r = 0; r < 16; ++r) {
    int row = r * 4 + ty;
    t[row][tx] = Vb[(size_t)(k0 + row) * D_ + (a0 + tx)];
  }
  __syncthreads();
#pragma unroll
  for (int r = 0; r < 16; ++r) {
    int row = r * 4 + ty;
    Vtb[(size_t)(a0 + row) * L_ + (k0 + tx)] = t[tx][row];
  }
}

__device__ __forceinline__ float block_red(float v, bool domax, float* red)
{
#pragma unroll
  for (int off = 32; off > 0; off >>= 1) {
    float o = __shfl_xor(v, off, 64);
    v = domax ? fmaxf(v, o) : (v + o);
  }
  __syncthreads();
  if ((threadIdx.x & 63) == 0) red[threadIdx.x >> 6] = v;
  __syncthreads();
  return domax ? fmaxf(fmaxf(red[0], red[1]), fmaxf(red[2], red[3]))
               : (red[0] + red[1] + red[2] + red[3]);
}

// One workgroup per row. Reads Ss,So (bf16, 8 elems/thread via uint4).
// Writes p_self fp32 and Psum bf16 (in-place over So).
__global__ __launch_bounds__(256) void softmax2(
    const ushort* __restrict__ S, float* __restrict__ pself)
{
  __shared__ float red[4];
  const size_t row = blockIdx.x;
  const int tid = threadIdx.x;
  const size_t half = (size_t)B_ * L_ * L_;

  const uint4* rs = (const uint4*)(S + row * L_);
  const uint4* ro = (const uint4*)(S + half + row * L_);
  uint4 us = rs[tid];
  uint4 uo = ro[tid];

  float vs[8], vo[8];
  const ushort* ps = (const ushort*)&us;
  const ushort* po = (const ushort*)&uo;
#pragma unroll
  for (int j = 0; j < 8; j++) { vs[j] = bf2f(ps[j]); vo[j] = bf2f(po[j]); }

  float ms = -3.0e38f, mo = -3.0e38f;
#pragma unroll
  for (int j = 0; j < 8; j++) { ms = fmaxf(ms, vs[j]); mo = fmaxf(mo, vo[j]); }
  ms = block_red(ms, true, red);
  mo = block_red(mo, true, red);

  float ss = 0.f, so = 0.f;
#pragma unroll
  for (int j = 0; j < 8; j++) {
    vs[j] = __expf(vs[j] - ms); ss += vs[j];
    vo[j] = __expf(vo[j] - mo); so += vo[j];
  }
  ss = block_red(ss, false, red);
  so = block_red(so, false, red);
  const float is = 1.f / ss, io = 1.f / so;

  float* pr = pself + row * (size_t)L_ + (size_t)tid * 8;
  float4 o0, o1;
  o0.x = vs[0] * is; o0.y = vs[1] * is; o0.z = vs[2] * is; o0.w = vs[3] * is;
  o1.x = vs[4] * is; o1.y = vs[5] * is; o1.z = vs[6] * is; o1.w = vs[7] * is;
  ((float4*)pr)[0] = o0;
  ((float4*)pr)[1] = o1;

  uint4 up;
  ushort* pp = (ushort*)&up;
#pragma unroll
  for (int j = 0; j < 8; j++) pp[j] = f2bf(vs[j] * is + vo[j] * io);
  ((uint4*)(S + half + row * L_))[tid] = up;   // in-place over So (all reads done)
}

// fp32 -> bf16, blockIdx.z selects source; dst slabs contiguous (n4*4 each)
__global__ __launch_bounds__(256) void cvt4(
    const float* __restrict__ s0, const float* __restrict__ s1,
    const float* __restrict__ s2, const float* __restrict__ s3,
    ushort* __restrict__ dst, int n4)
{
  const float* s = (blockIdx.z == 0) ? s0 : (blockIdx.z == 1) ? s1
                   : (blockIdx.z == 2) ? s2 : s3;
  ushort* d = dst + (size_t)blockIdx.z * (size_t)n4 * 4;
  const float4* sv = (const float4*)s;
  ushort4* dv = (ushort4*)d;
  for (int i = blockIdx.x * 256 + threadIdx.x; i < n4; i += gridDim.x * 256) {
    float4 f = sv[i];
    ushort4 o; o.x = f2bf(f.x); o.y = f2bf(f.y); o.z = f2bf(f.z); o.w = f2bf(f.w);
    dv[i] = o;
  }
}

extern "C" void kernel_launch(void* const* d_in, const int* in_sizes, int n_in,
                              void* d_out, int out_size, void* d_ws, size_t ws_size,
                              hipStream_t stream)
{
  const float* x    = (const float*)d_in[0];
  const float* qry  = (const float*)d_in[1];
  const float* val  = (const float*)d_in[2];
  const float* mask = (const float*)d_in[3];
  const float* Wk   = (const float*)d_in[4];
  const float* Wqs  = (const float*)d_in[5];
  const float* Wqo  = (const float*)d_in[6];
  const float* Wv   = (const float*)d_in[7];

  const size_t NE = (size_t)B_ * L_ * D_;    // 16,777,216
  const size_t NW = (size_t)D_ * D_;         // 1,048,576
  const size_t NS = (size_t)B_ * L_ * L_;    // 33,554,432 (one score set)

  float*  out   = (float*)d_out;
  float*  pself = out + NE;                  // [8,2048,2048] fp32

  ushort* ob = (ushort*)d_out;               // ushort view of d_out
  ushort* Qs   = ob;                         // [0, NE)
  ushort* Qo   = ob + NE;                    // [NE, 2NE)
  ushort* Kb   = ob + 2 * NE;                // [2NE, 3NE)  (in p_self region)
  ushort* Vtmp = ob + 3 * NE;                // [3NE, 4NE)

  char* ws = (char*)d_ws;
  ushort* xb = (ushort*)ws;                  // phase-1: xb qb vb W4
  ushort* W4 = xb + 3 * NE;
  ushort* Sc = (ushort*)ws;                  // phase-2: Ss | So (then Psum)
  ushort* Psum = Sc + NS;                    // = So, bf16 in place
  ushort* Vt = (ushort*)(ws + (size_t)134217728);

  const float scale = 0.03125f;              // 1/sqrt(1024)

  // 1) fp32 -> bf16 (weights in proj order: Wqs, Wqo, Wk, Wv)
  cvt4<<<dim3(4096, 1, 3), 256, 0, stream>>>(x, qry, val, nullptr, xb, (int)(NE / 4));
  cvt4<<<dim3(1024, 1, 4), 256, 0, stream>>>(Wqs, Wqo, Wk, Wv, W4, (int)(NW / 4));

  // 2) projections, merged: z=0..3 -> Qs, Qo, Kb, Vtmp; M=16384,N=1024,K=1024
  gemm_bt<0><<<dim3(128, 8, 4), 256, 0, stream>>>(
      xb, (long long)NE, D_, W4, (long long)NW, D_,
      ob, (long long)NE, D_, D_, nullptr, 1.f);

  // 3) V -> V^T
  transpose_bf16<<<dim3(L_ / 64, D_ / 64, B_), 256, 0, stream>>>(Vtmp, Vt);

  // 4) scores, merged: z=0..15 (z<8: Qs->Ss, z>=8: Qo->So); M=N=2048,K=1024
  gemm_bt<1><<<dim3(16, 16, 16), 256, 0, stream>>>(
      Qs, (long long)L_ * D_, D_, Kb, (long long)L_ * D_, D_,
      Sc, (long long)L_ * L_, L_, D_, mask, scale);

  // 5) softmax both sets; p_self fp32; Psum bf16 in place over So
  softmax2<<<dim3(B_ * L_, 1, 1), 256, 0, stream>>>(Sc, pself);

  // 6) out = Psum @ Vt^T: M=2048, N=1024, K=2048, z=0..7
  gemm_bt<2><<<dim3(16, 8, 8), 256, 0, stream>>>(
      Psum, (long long)L_ * L_, L_, Vt, (long long)D_ * L_, L_,
      out, (long long)L_ * D_, D_, L_, nullptr, 1.f);
}